// Round 6
// baseline (559.330 us; speedup 1.0000x reference)
//
#include <hip/hip_runtime.h>

typedef __attribute__((ext_vector_type(8))) short vbf8;   // 8 bf16 = 4 VGPR (K=32 MFMA A/B frag)
typedef __attribute__((ext_vector_type(4))) float vf4;    // MFMA C/D frag

#define NT 53
#define CD 256
#define NH 8
#define HIMG 65536          // per-head global frag image: QK(32K) + V(16K) + biasT f32(16K)
#define PROJ_OFF 524288     // proj_w bf16 image offset in ws
#define QBS_OFF  655360     // scaled qkv_b table (768 f32)
#define ATTN_OFF 1048576    // attn intermediate offset in ws

#define LOG2E 1.4426950408889634f
#define SCALE 0.17677669529663687f   // 32^-0.5

__device__ __forceinline__ unsigned pk2(float a, float b) {
    unsigned r;
    asm("v_cvt_pk_bf16_f32 %0, %1, %2" : "=v"(r) : "v"(a), "v"(b));
    return r;
}

// Transpose MFMA C-layout (col=c, rows over g,reg) into K=32-frag layout
// (lane keeps col; 8 contiguous row-elems per lane). Proven rounds 1-5.
__device__ __forceinline__ vbf8 xpose(vf4 A, vf4 B, int odd) {
    unsigned A0 = pk2(A[0], A[1]), A1 = pk2(A[2], A[3]);
    unsigned B0 = pk2(B[0], B[1]), B1 = pk2(B[2], B[3]);
    asm("v_permlane32_swap_b32 %0, %1" : "+v"(A0), "+v"(B0));
    asm("v_permlane32_swap_b32 %0, %1" : "+v"(A1), "+v"(B1));
    unsigned s0 = (unsigned)__shfl_xor((int)B0, 16, 64);
    unsigned s1 = (unsigned)__shfl_xor((int)B1, 16, 64);
    unsigned t0 = (unsigned)__shfl_xor((int)A0, 16, 64);
    unsigned t1 = (unsigned)__shfl_xor((int)A1, 16, 64);
    union { unsigned u[4]; vbf8 v; } r;
    r.u[0] = odd ? s0 : A0;
    r.u[1] = odd ? s1 : A1;
    r.u[2] = odd ? B0 : t0;
    r.u[3] = odd ? B1 : t1;
    return r.v;
}

__device__ __forceinline__ void gl_lds16(const void* g, void* l) {
    __builtin_amdgcn_global_load_lds((const __attribute__((address_space(1))) unsigned*)g,
                                     (__attribute__((address_space(3))) unsigned*)l, 16, 0, 0);
}

// ---------------- Kernel 0: prep ----------------
// ws: [0,512K) per-head frag images read per-lane by k1:
//   QK frags F=0..31 (F=mt*8+ks; mt 0-1 = Wq*scale*log2e rows, mt 2-3 = Wk rows):
//     lane l holds W[row=mt*16+(l&15)][ks*32+(l>>4)*8 ..+8] bf16  at F*1024+l*16
//   V  frags F=32..47 (nv*8+ks), same per-lane layout,            at F*1024+l*16
//   bias frags F=0..15 (mk*4+nq) f32x4: lane l = bias[key=mk*16+(l>>4)*4+e][q=nq*16+(l&15)]
//     at 49152 + F*1024 + l*16   (pre-masked, * log2e)
// [512K,640K) proj_w bf16 swizzled LDS image (k2); [QBS_OFF) scaled qkv_b.
__global__ void k0_prep(const float* __restrict__ qkv_w, const float* __restrict__ tbl,
                        const float* __restrict__ proj_w, const float* __restrict__ qkv_b,
                        char* __restrict__ ws)
{
    const int u = (int)blockIdx.x * 256 + (int)threadIdx.x;
    if (u < 24576) {
        // weight frags: h(8) x F(48) x l(64)
        const int h = u / 3072, r = u - h * 3072;
        const int F = r >> 6, l = r & 63;
        const int c = l & 15, g = l >> 4;
        const int ks = F & 7;
        int srcrow; float sc = 1.0f;
        if (F < 16)      { srcrow = h * 32 + (F >> 3) * 16 + c; sc = SCALE * LOG2E; }
        else if (F < 32) { srcrow = 256 + h * 32 + ((F >> 3) - 2) * 16 + c; }
        else             { srcrow = 512 + h * 32 + ((F - 32) >> 3) * 16 + c; }
        const float* src = qkv_w + (size_t)srcrow * 256 + ks * 32 + g * 8;
        vf4 a = *(const vf4*)src;
        vf4 b = *(const vf4*)(src + 4);
        union { unsigned w[4]; vbf8 v; } rv;
        rv.w[0] = pk2(a[0] * sc, a[1] * sc); rv.w[1] = pk2(a[2] * sc, a[3] * sc);
        rv.w[2] = pk2(b[0] * sc, b[1] * sc); rv.w[3] = pk2(b[2] * sc, b[3] * sc);
        *(vbf8*)(ws + (size_t)h * HIMG + F * 1024 + l * 16) = rv.v;
    } else if (u < 32768) {
        // bias frags: h(8) x F(16) x l(64)
        const int t = u - 24576;
        const int h = t >> 10, r2 = t & 1023;
        const int F = r2 >> 6, l = r2 & 63;
        const int mk = F >> 2, nq = F & 3;
        const int c = l & 15, g = l >> 4;
        vf4 rv;
        #pragma unroll
        for (int e = 0; e < 4; ++e) {
            const int key = mk * 16 + g * 4 + e;
            const int q   = nq * 16 + c;
            float bv;
            if (key >= NT) bv = -1e30f;                          // mask pad keys
            else if (key < 4 || q < 4 || q >= NT) bv = 0.0f;     // carrier rows/cols
            else {
                const int i = q - 4, j = key - 4;
                const int idx = ((i / 7) - (j / 7) + 6) * 13 + ((i % 7) - (j % 7) + 6);
                bv = tbl[idx * NH + h] * LOG2E;
            }
            rv[e] = bv;
        }
        *(vf4*)(ws + (size_t)h * HIMG + 49152 + F * 1024 + l * 16) = rv;
    } else if (u < 40960) {
        // proj_w bf16 image: kc(4) x row(256) x seg(8) (unchanged, for k2)
        const int t = u - 32768;
        const int kc = t >> 11, rem = t & 2047;
        const int row = rem >> 3, seg = rem & 7;
        const float* src = proj_w + (size_t)row * 256 + kc * 64 + seg * 8;
        vf4 a = *(const vf4*)src;
        vf4 b = *(const vf4*)(src + 4);
        union { unsigned w[4]; vbf8 v; } rv;
        rv.w[0] = pk2(a[0], a[1]); rv.w[1] = pk2(a[2], a[3]);
        rv.w[2] = pk2(b[0], b[1]); rv.w[3] = pk2(b[2], b[3]);
        char* dst = ws + PROJ_OFF + kc * 32768 + row * 128 + ((seg * 16) ^ ((row & 7) << 4));
        *(vbf8*)dst = rv.v;
    } else if (u < 41152) {
        // scaled qkv_b: [0,256) *scale*log2e (Q), rest raw
        const int i = (u - 40960) * 4;
        float* dst = (float*)(ws + QBS_OFF);
        #pragma unroll
        for (int e = 0; e < 4; ++e) {
            const int j = i + e;
            dst[j] = qkv_b[j] * (j < 256 ? SCALE * LOG2E : 1.0f);
        }
    }
}

// ---------------- Kernel 1: fused QKV + windowed attention ----------------
// Block = 256 thr / 4 waves / ONE window. Wave w computes heads {w, w+4}.
// x lives in LDS in MFMA-frag layout (32 KB, lane-XOR perm, conflict-free
// ds_read_b128); weights/bias stream per-lane from L2-resident frag images.
// No barriers after x-staging. 4 waves/SIMD (vs 2 in rounds 1-5).
__launch_bounds__(256, 4)
__global__ void k1_fused(const float* __restrict__ x,
                         const float* __restrict__ qbs,
                         const char* __restrict__ wimg,
                         short* __restrict__ attnH,
                         int win0, int Mtot)
{
    __shared__ char xlds[32768];

    const int tid  = threadIdx.x;
    const int wave = tid >> 6;
    const int lane = tid & 63;
    const int c    = lane & 15;
    const int g    = lane >> 4;
    const int odd  = g & 1;
    const int win  = win0 + (int)blockIdx.x;

    // ---- stage x into frag-layout LDS; pad tokens 53..63 zeroed ----
    {
        const float* xb = x + (size_t)win * (NT * CD);
        #pragma unroll
        for (int i = 0; i < 8; ++i) {
            const int u   = tid + i * 256;          // 2048 units of 16B
            const int row = u >> 5, seg = u & 31;
            const int F   = (row >> 4) * 8 + (seg >> 2);
            const int dl  = (seg & 3) * 16 + (row & 15);
            char* dst = xlds + F * 1024 + (dl ^ (F & 7)) * 16;
            if (row < NT) {
                const float* s = xb + row * CD + seg * 8;
                vf4 a = *(const vf4*)s;
                vf4 b = *(const vf4*)(s + 4);
                union { unsigned w[4]; vbf8 v; } r;
                r.w[0] = pk2(a[0], a[1]); r.w[1] = pk2(a[2], a[3]);
                r.w[2] = pk2(b[0], b[1]); r.w[3] = pk2(b[2], b[3]);
                *(vbf8*)dst = r.v;
            } else {
                vbf8 z = {0, 0, 0, 0, 0, 0, 0, 0};
                *(vbf8*)dst = z;
            }
        }
    }
    __syncthreads();

    auto rdX = [&](int F) -> vbf8 {
        return *(const vbf8*)(xlds + F * 1024 + ((lane ^ (F & 7)) * 16));
    };

    #pragma unroll 1
    for (int hh = 0; hh < 2; ++hh) {
        const int h = wave + hh * 4;
        const char* wh = wimg + (size_t)h * HIMG;

        auto ldW = [&](int F) -> vbf8 {
            return *(const vbf8*)(wh + F * 1024 + lane * 16);
        };

        // ---------- merged QK cluster: [Wq;Wk](64ch) @ x^T, biases as C-init ----------
        vf4 qk[4][4];    // [ch-tile][token-tile]; ch 0-31 = q-dims, 32-63 = k-dims
        #pragma unroll
        for (int mt = 0; mt < 4; ++mt) {
            const float* bsrc = (mt < 2) ? (qbs + h * 32 + mt * 16 + g * 4)
                                         : (qbs + 256 + h * 32 + (mt - 2) * 16 + g * 4);
            vf4 bi = *(const vf4*)bsrc;
            #pragma unroll
            for (int nt = 0; nt < 4; ++nt) qk[mt][nt] = bi;
        }
        __builtin_amdgcn_s_setprio(1);
        #pragma unroll
        for (int ks = 0; ks < 8; ++ks) {
            vbf8 w0 = ldW(ks), w1 = ldW(8 + ks), w2 = ldW(16 + ks), w3 = ldW(24 + ks);
            vbf8 x0 = rdX(ks), x1 = rdX(8 + ks), x2 = rdX(16 + ks), x3 = rdX(24 + ks);
            qk[0][0] = __builtin_amdgcn_mfma_f32_16x16x32_bf16(w0, x0, qk[0][0], 0, 0, 0);
            qk[0][1] = __builtin_amdgcn_mfma_f32_16x16x32_bf16(w0, x1, qk[0][1], 0, 0, 0);
            qk[0][2] = __builtin_amdgcn_mfma_f32_16x16x32_bf16(w0, x2, qk[0][2], 0, 0, 0);
            qk[0][3] = __builtin_amdgcn_mfma_f32_16x16x32_bf16(w0, x3, qk[0][3], 0, 0, 0);
            qk[1][0] = __builtin_amdgcn_mfma_f32_16x16x32_bf16(w1, x0, qk[1][0], 0, 0, 0);
            qk[1][1] = __builtin_amdgcn_mfma_f32_16x16x32_bf16(w1, x1, qk[1][1], 0, 0, 0);
            qk[1][2] = __builtin_amdgcn_mfma_f32_16x16x32_bf16(w1, x2, qk[1][2], 0, 0, 0);
            qk[1][3] = __builtin_amdgcn_mfma_f32_16x16x32_bf16(w1, x3, qk[1][3], 0, 0, 0);
            qk[2][0] = __builtin_amdgcn_mfma_f32_16x16x32_bf16(w2, x0, qk[2][0], 0, 0, 0);
            qk[2][1] = __builtin_amdgcn_mfma_f32_16x16x32_bf16(w2, x1, qk[2][1], 0, 0, 0);
            qk[2][2] = __builtin_amdgcn_mfma_f32_16x16x32_bf16(w2, x2, qk[2][2], 0, 0, 0);
            qk[2][3] = __builtin_amdgcn_mfma_f32_16x16x32_bf16(w2, x3, qk[2][3], 0, 0, 0);
            qk[3][0] = __builtin_amdgcn_mfma_f32_16x16x32_bf16(w3, x0, qk[3][0], 0, 0, 0);
            qk[3][1] = __builtin_amdgcn_mfma_f32_16x16x32_bf16(w3, x1, qk[3][1], 0, 0, 0);
            qk[3][2] = __builtin_amdgcn_mfma_f32_16x16x32_bf16(w3, x2, qk[3][2], 0, 0, 0);
            qk[3][3] = __builtin_amdgcn_mfma_f32_16x16x32_bf16(w3, x3, qk[3][3], 0, 0, 0);
        }
        __builtin_amdgcn_s_setprio(0);
        vbf8 qf[4], kf[4];
        #pragma unroll
        for (int nt = 0; nt < 4; ++nt) qf[nt] = xpose(qk[0][nt], qk[1][nt], odd);
        #pragma unroll
        for (int nt = 0; nt < 4; ++nt) kf[nt] = xpose(qk[2][nt], qk[3][nt], odd);

        // ---------- V cluster: x @ Wv^T, bias as C-init ----------
        vbf8 vfr[2][2];           // [hd-tile][key-block]
        {
            vf4 va[4][2];
            #pragma unroll
            for (int nv = 0; nv < 2; ++nv) {
                const float vb = qbs[512 + h * 32 + nv * 16 + c];
                vf4 bi = {vb, vb, vb, vb};
                #pragma unroll
                for (int mt = 0; mt < 4; ++mt) va[mt][nv] = bi;
            }
            __builtin_amdgcn_s_setprio(1);
            #pragma unroll
            for (int ks = 0; ks < 8; ++ks) {
                vbf8 v0 = ldW(32 + ks), v1 = ldW(40 + ks);
                vbf8 x0 = rdX(ks), x1 = rdX(8 + ks), x2 = rdX(16 + ks), x3 = rdX(24 + ks);
                va[0][0] = __builtin_amdgcn_mfma_f32_16x16x32_bf16(x0, v0, va[0][0], 0, 0, 0);
                va[1][0] = __builtin_amdgcn_mfma_f32_16x16x32_bf16(x1, v0, va[1][0], 0, 0, 0);
                va[2][0] = __builtin_amdgcn_mfma_f32_16x16x32_bf16(x2, v0, va[2][0], 0, 0, 0);
                va[3][0] = __builtin_amdgcn_mfma_f32_16x16x32_bf16(x3, v0, va[3][0], 0, 0, 0);
                va[0][1] = __builtin_amdgcn_mfma_f32_16x16x32_bf16(x0, v1, va[0][1], 0, 0, 0);
                va[1][1] = __builtin_amdgcn_mfma_f32_16x16x32_bf16(x1, v1, va[1][1], 0, 0, 0);
                va[2][1] = __builtin_amdgcn_mfma_f32_16x16x32_bf16(x2, v1, va[2][1], 0, 0, 0);
                va[3][1] = __builtin_amdgcn_mfma_f32_16x16x32_bf16(x3, v1, va[3][1], 0, 0, 0);
            }
            __builtin_amdgcn_s_setprio(0);
            #pragma unroll
            for (int nv = 0; nv < 2; ++nv)
                #pragma unroll
                for (int kp = 0; kp < 2; ++kp)
                    vfr[nv][kp] = xpose(va[2 * kp][nv], va[2 * kp + 1][nv], odd);
        }

        // ---------- S^T = k @ q^T, bias frags as C-init (from L2 image) ----------
        vf4 st[4][4];
        #pragma unroll
        for (int mk = 0; mk < 4; ++mk)
            #pragma unroll
            for (int nq = 0; nq < 4; ++nq)
                st[mk][nq] = *(const vf4*)(wh + 49152 + (mk * 4 + nq) * 1024 + lane * 16);
        __builtin_amdgcn_s_setprio(1);
        #pragma unroll
        for (int mk = 0; mk < 4; ++mk)
            #pragma unroll
            for (int nq = 0; nq < 4; ++nq)
                st[mk][nq] = __builtin_amdgcn_mfma_f32_16x16x32_bf16(kf[mk], qf[nq], st[mk][nq], 0, 0, 0);
        __builtin_amdgcn_s_setprio(0);

        // ---------- softmax over keys (exp2 domain) ----------
        float linv[4];
        #pragma unroll
        for (int nq = 0; nq < 4; ++nq) {
            float mx = -3e38f;
            #pragma unroll
            for (int mk = 0; mk < 4; ++mk)
                #pragma unroll
                for (int r = 0; r < 4; ++r) mx = fmaxf(mx, st[mk][nq][r]);
            mx = fmaxf(mx, __shfl_xor(mx, 16, 64));
            mx = fmaxf(mx, __shfl_xor(mx, 32, 64));
            float sum = 0.f;
            #pragma unroll
            for (int mk = 0; mk < 4; ++mk)
                #pragma unroll
                for (int r = 0; r < 4; ++r) {
                    float p = exp2f(st[mk][nq][r] - mx);
                    st[mk][nq][r] = p;
                    sum += p;
                }
            sum += __shfl_xor(sum, 16, 64);
            sum += __shfl_xor(sum, 32, 64);
            linv[nq] = 1.f / sum;
        }

        // ---------- pT frags ----------
        vbf8 pfr[4][2];
        #pragma unroll
        for (int nq = 0; nq < 4; ++nq)
            #pragma unroll
            for (int kp = 0; kp < 2; ++kp)
                pfr[nq][kp] = xpose(st[2 * kp][nq], st[2 * kp + 1][nq], odd);

        // ---------- out^T = vT @ pT ----------
        vf4 ot[2][4];
        #pragma unroll
        for (int mt = 0; mt < 2; ++mt)
            #pragma unroll
            for (int nq = 0; nq < 4; ++nq) { vf4 z = {0.f,0.f,0.f,0.f}; ot[mt][nq] = z; }
        __builtin_amdgcn_s_setprio(1);
        #pragma unroll
        for (int kp = 0; kp < 2; ++kp)
            #pragma unroll
            for (int mt = 0; mt < 2; ++mt)
                #pragma unroll
                for (int nq = 0; nq < 4; ++nq)
                    ot[mt][nq] = __builtin_amdgcn_mfma_f32_16x16x32_bf16(vfr[mt][kp], pfr[nq][kp], ot[mt][nq], 0, 0, 0);
        __builtin_amdgcn_s_setprio(0);

        // ---------- normalize + write attnH[h][mrow][32] (16B/lane) ----------
        #pragma unroll
        for (int nq = 0; nq < 4; ++nq) {
            vf4 A = ot[0][nq], B = ot[1][nq];
            #pragma unroll
            for (int r = 0; r < 4; ++r) { A[r] *= linv[nq]; B[r] *= linv[nq]; }
            vbf8 o = xpose(A, B, odd);
            const int qq = nq * 16 + c;
            if (qq < NT) {
                const int mrow = (win - win0) * NT + qq;
                *(vbf8*)(attnH + ((size_t)h * Mtot + mrow) * 32 + g * 8) = o;
            }
        }
    }
}

// ---------------- Kernel 2: output projection GEMM (unchanged, proven) ----------------
__launch_bounds__(256, 4)
__global__ void k2_proj(const short* __restrict__ attnH,
                        const char* __restrict__ projimg,
                        const float* __restrict__ proj_b,
                        float* __restrict__ out,
                        int Mtot)
{
    __shared__ char a_lds[8192];      // [64 rows][128 B] swizzled
    __shared__ char b_lds[32768];     // [256 rows][128 B] swizzled

    const int tid  = threadIdx.x;
    const int wave = tid >> 6;
    const int lane = tid & 63;
    const int c    = lane & 15;
    const int g    = lane >> 4;
    const int m0   = (int)blockIdx.x * 64;

    vf4 acc[4][4];
    #pragma unroll
    for (int mt = 0; mt < 4; ++mt)
        #pragma unroll
        for (int nt = 0; nt < 4; ++nt) { vf4 z = {0.f,0.f,0.f,0.f}; acc[mt][nt] = z; }

    for (int kc = 0; kc < 4; ++kc) {
        __syncthreads();
        // stage A tile via DMA with swizzle-compensated per-lane source
        #pragma unroll
        for (int rr = 0; rr < 2; ++rr) {
            const int u    = tid + rr * 256;         // 512 units
            const int row  = u >> 3;
            const int sub  = u & 7;
            const int subs = sub ^ (row & 7);
            const int head = kc * 2 + (subs >> 2);
            const int kk   = (subs & 3) * 8;
            int mrow = m0 + row; if (mrow >= Mtot) mrow = Mtot - 1;
            gl_lds16(attnH + ((size_t)head * Mtot + mrow) * 32 + kk,
                     &a_lds[(rr * 256 + wave * 64) * 16]);
        }
        // stage B tile (pre-swizzled image, linear DMA)
        #pragma unroll
        for (int it = 0; it < 8; ++it) {
            const int u = tid + it * 256;            // 2048 units
            gl_lds16(projimg + (size_t)kc * 32768 + (size_t)u * 16,
                     &b_lds[(it * 256 + wave * 64) * 16]);
        }
        __syncthreads();
        #pragma unroll
        for (int ksub = 0; ksub < 2; ++ksub) {
            vbf8 af[4], bfr[4];
            #pragma unroll
            for (int mt = 0; mt < 4; ++mt) {
                const int row = mt * 16 + c;
                af[mt] = *(const vbf8*)(a_lds + row * 128 + (((ksub * 64) + g * 16) ^ ((row & 7) << 4)));
            }
            #pragma unroll
            for (int nt = 0; nt < 4; ++nt) {
                const int row = wave * 64 + nt * 16 + c;
                bfr[nt] = *(const vbf8*)(b_lds + row * 128 + (((ksub * 64) + g * 16) ^ ((row & 7) << 4)));
            }
            #pragma unroll
            for (int mt = 0; mt < 4; ++mt)
                #pragma unroll
                for (int nt = 0; nt < 4; ++nt)
                    acc[mt][nt] = __builtin_amdgcn_mfma_f32_16x16x32_bf16(af[mt], bfr[nt], acc[mt][nt], 0, 0, 0);
        }
    }
    #pragma unroll
    for (int nt = 0; nt < 4; ++nt) {
        const int n = wave * 64 + nt * 16 + c;
        const float pb = proj_b[n];
        #pragma unroll
        for (int mt = 0; mt < 4; ++mt)
            #pragma unroll
            for (int r = 0; r < 4; ++r) {
                const int m = m0 + mt * 16 + g * 4 + r;
                if (m < Mtot) out[(size_t)m * 256 + n] = acc[mt][nt][r] + pb;
            }
    }
}

extern "C" void kernel_launch(void* const* d_in, const int* in_sizes, int n_in,
                              void* d_out, int out_size, void* d_ws, size_t ws_size,
                              hipStream_t stream)
{
    const float* x      = (const float*)d_in[0];
    const float* qkv_w  = (const float*)d_in[1];
    const float* qkv_b  = (const float*)d_in[2];
    const float* proj_w = (const float*)d_in[3];
    const float* proj_b = (const float*)d_in[4];
    const float* tbl    = (const float*)d_in[5];
    float* out = (float*)d_out;
    char* ws   = (char*)d_ws;

    k0_prep<<<161, 256, 0, stream>>>(qkv_w, tbl, proj_w, qkv_b, ws);

    short* attn = (short*)(ws + ATTN_OFF);
    const float* qbs = (const float*)(ws + QBS_OFF);
    const size_t bpw = (size_t)NT * 32 * 2 * NH;   // bytes per window in attn area
    long cw = (ws_size > ATTN_OFF) ? (long)((ws_size - ATTN_OFF) / bpw) : 1;
    if (cw > 4096) cw = 4096;
    if (cw < 1) cw = 1;
    for (int start = 0; start < 4096; start += (int)cw) {
        int count = 4096 - start; if (count > (int)cw) count = (int)cw;
        const int Mc = count * NT;
        k1_fused<<<count, 256, 0, stream>>>(x, qbs, ws, attn, start, Mc);
        k2_proj<<<(Mc + 63) / 64, 256, 0, stream>>>(attn, ws + PROJ_OFF, proj_b,
                                                    out + (size_t)start * NT * CD, Mc);
    }
    (void)in_sizes; (void)n_in; (void)out_size;
}

// Round 7
// 487.930 us; speedup vs baseline: 1.1463x; 1.1463x over previous
//
#include <hip/hip_runtime.h>

typedef __attribute__((ext_vector_type(8))) short vbf8;   // 8 bf16 = 4 VGPR (K=32 MFMA A/B frag)
typedef __attribute__((ext_vector_type(4))) float vf4;    // MFMA C/D frag

#define NT 53
#define CD 256
#define NH 8
#define HIMG 65536          // per-head LDS image: Wq(16K)+Wk(16K)+Wv(16K)+biasT f32(16K)
#define PROJ_OFF 524288     // proj_w bf16 image offset in ws
#define QBS_OFF  655360     // scaled qkv_b table (768 f32)
#define ATTN_OFF 1048576    // attn intermediate offset in ws

#define LOG2E 1.4426950408889634f
#define SCALE 0.17677669529663687f   // 32^-0.5

__device__ __forceinline__ unsigned pk2(float a, float b) {
    unsigned r;
    asm("v_cvt_pk_bf16_f32 %0, %1, %2" : "=v"(r) : "v"(a), "v"(b));
    return r;
}

// Transpose MFMA C-layout (col=c, rows over g,reg) into K=32-frag layout
// (lane keeps col; 8 contiguous row-elems per lane). Proven rounds 1-6.
__device__ __forceinline__ vbf8 xpose(vf4 A, vf4 B, int odd) {
    unsigned A0 = pk2(A[0], A[1]), A1 = pk2(A[2], A[3]);
    unsigned B0 = pk2(B[0], B[1]), B1 = pk2(B[2], B[3]);
    asm("v_permlane32_swap_b32 %0, %1" : "+v"(A0), "+v"(B0));
    asm("v_permlane32_swap_b32 %0, %1" : "+v"(A1), "+v"(B1));
    unsigned s0 = (unsigned)__shfl_xor((int)B0, 16, 64);
    unsigned s1 = (unsigned)__shfl_xor((int)B1, 16, 64);
    unsigned t0 = (unsigned)__shfl_xor((int)A0, 16, 64);
    unsigned t1 = (unsigned)__shfl_xor((int)A1, 16, 64);
    union { unsigned u[4]; vbf8 v; } r;
    r.u[0] = odd ? s0 : A0;
    r.u[1] = odd ? s1 : A1;
    r.u[2] = odd ? B0 : t0;
    r.u[3] = odd ? B1 : t1;
    return r.v;
}

__device__ __forceinline__ void gl_lds16(const void* g, void* l) {
    __builtin_amdgcn_global_load_lds((const __attribute__((address_space(1))) unsigned*)g,
                                     (__attribute__((address_space(3))) unsigned*)l, 16, 0, 0);
}

// ---------------- Kernel 0: prep (identical to round 5, proven) ----------------
__global__ void k0_prep(const float* __restrict__ qkv_w, const float* __restrict__ tbl,
                        const float* __restrict__ proj_w, const float* __restrict__ qkv_b,
                        char* __restrict__ ws)
{
    const int u = (int)blockIdx.x * 256 + (int)threadIdx.x;
    if (u < 24576) {
        // qkv weight images: h(8) x sec(3) x row(32) x seg(32 units of 8 bf16)
        const int h = u / 3072, rem = u - h * 3072;
        const int sec = rem >> 10, rem2 = rem & 1023;
        const int row = rem2 >> 5, seg = rem2 & 31;
        const float* src = qkv_w + ((size_t)(sec * 256 + h * 32 + row)) * 256 + seg * 8;
        const float sc = (sec == 0) ? SCALE * LOG2E : 1.0f;
        vf4 a = *(const vf4*)src;
        vf4 b = *(const vf4*)(src + 4);
        union { unsigned w[4]; vbf8 v; } r;
        r.w[0] = pk2(a[0] * sc, a[1] * sc); r.w[1] = pk2(a[2] * sc, a[3] * sc);
        r.w[2] = pk2(b[0] * sc, b[1] * sc); r.w[3] = pk2(b[2] * sc, b[3] * sc);
        char* dst = ws + (size_t)h * HIMG + sec * 16384 + row * 512 + ((seg * 16) ^ ((row & 7) << 4));
        *(vbf8*)dst = r.v;
    } else if (u < 32768) {
        // biasT images (f32, *log2e): h(8) x q(64) x seg(16 units of 4 f32); biasT[q][key]
        const int t = u - 24576;
        const int h = t >> 10, rem = t & 1023;
        const int q = rem >> 4, seg = rem & 15;
        vf4 r;
        #pragma unroll
        for (int e = 0; e < 4; ++e) {
            const int key = seg * 4 + e;
            float bv;
            if (key >= NT) bv = -1e30f;                          // mask pad keys
            else if (key < 4 || q < 4 || q >= NT) bv = 0.0f;     // carrier rows/cols
            else {
                const int i = q - 4, j = key - 4;
                const int idx = ((i / 7) - (j / 7) + 6) * 13 + ((i % 7) - (j % 7) + 6);
                bv = tbl[idx * NH + h] * LOG2E;
            }
            r[e] = bv;
        }
        char* dst = ws + (size_t)h * HIMG + 49152 + q * 256 + ((seg * 16) ^ ((q & 7) << 4));
        *(vf4*)dst = r;
    } else if (u < 40960) {
        // proj_w bf16 image: kc(4) x row(256) x seg(8)
        const int t = u - 32768;
        const int kc = t >> 11, rem = t & 2047;
        const int row = rem >> 3, seg = rem & 7;
        const float* src = proj_w + (size_t)row * 256 + kc * 64 + seg * 8;
        vf4 a = *(const vf4*)src;
        vf4 b = *(const vf4*)(src + 4);
        union { unsigned w[4]; vbf8 v; } r;
        r.w[0] = pk2(a[0], a[1]); r.w[1] = pk2(a[2], a[3]);
        r.w[2] = pk2(b[0], b[1]); r.w[3] = pk2(b[2], b[3]);
        char* dst = ws + PROJ_OFF + kc * 32768 + row * 128 + ((seg * 16) ^ ((row & 7) << 4));
        *(vbf8*)dst = r.v;
    } else if (u < 41152) {
        // scaled qkv_b: [0,256) *scale*log2e (Q), rest raw
        const int i = (u - 40960) * 4;
        float* dst = (float*)(ws + QBS_OFF);
        #pragma unroll
        for (int e = 0; e < 4; ++e) {
            const int j = i + e;
            dst[j] = qkv_b[j] * (j < 256 ? SCALE * LOG2E : 1.0f);
        }
    }
}

// ---------------- Kernel 1: fused QKV + windowed attention ----------------
// Proven round-5 config: 512 threads, 8 waves, one window/wave, 128 KB
// double-buffered head image, 1 barrier/head. Round-7 changes:
//  (a) merged QK mega-cluster: 128 MFMAs in one ks-loop (r6-verified math,
//      r5 image), removing the q/k cluster boundary;
//  (b) per-nq fused tail: softmax -> pT-xpose -> PV -> normalize -> write per
//      q-tile, so PV MFMAs overlap the next tile's softmax VALU and st/ot
//      registers retire incrementally.
__launch_bounds__(512, 2)
__global__ void k1_fused(const float* __restrict__ x,
                         const float* __restrict__ qbs,
                         const char* __restrict__ himg,
                         short* __restrict__ attnH,
                         int win0, int Mtot)
{
    __shared__ char lds[2][HIMG];

    const int tid  = threadIdx.x;
    const int wave = tid >> 6;
    const int lane = tid & 63;
    const int c    = lane & 15;
    const int g    = lane >> 4;
    const int odd  = g & 1;
    const int win  = win0 + (int)blockIdx.x * 8 + wave;

    auto stage = [&](int h, int buf) {
        const char* src = himg + (size_t)h * HIMG;
        #pragma unroll
        for (int i = 0; i < 8; ++i) {
            const int u = tid + i * 512;                       // 16B unit index
            gl_lds16(src + (size_t)u * 16, &lds[buf][(i * 512 + wave * 64) * 16]);
        }
    };

    stage(0, 0);   // prologue: head-0 image

    // ---- x fragments: xf[t16][ks]: lane holds x[t16*16+c][ks*32+g*8 .. +8] (bf16)
    vbf8 xf[4][8];
    {
        const float* xb = x + (size_t)win * (NT * CD);
        #pragma unroll
        for (int mt = 0; mt < 4; ++mt) {
            const int row = mt * 16 + c;
            const float* src = xb + row * CD + g * 8;
            #pragma unroll
            for (int ks = 0; ks < 8; ++ks) {
                vbf8 z = {0, 0, 0, 0, 0, 0, 0, 0};
                if (row < NT) {
                    vf4 a = *(const vf4*)(src + ks * 32);
                    vf4 b = *(const vf4*)(src + ks * 32 + 4);
                    union { unsigned w[4]; vbf8 v; } r;
                    r.w[0] = pk2(a[0], a[1]); r.w[1] = pk2(a[2], a[3]);
                    r.w[2] = pk2(b[0], b[1]); r.w[3] = pk2(b[2], b[3]);
                    z = r.v;
                }
                xf[mt][ks] = z;
            }
        }
    }
    __syncthreads();   // head-0 image staged (barrier drains vmcnt)

    #pragma unroll 1
    for (int h = 0; h < NH; ++h) {
        const int cur = h & 1;
        if (h < 7) stage(h + 1, cur ^ 1);          // prefetch next head under compute
        const char* wb = lds[cur];

        auto rdW = [&](int sec, int rr, int ks) -> vbf8 {
            const int byte = sec * 16384 + rr * 512 + (((ks * 64) + g * 16) ^ ((rr & 7) << 4));
            return *(const vbf8*)(wb + byte);
        };

        // ---------- merged QK cluster: [Wq*scale*log2e ; Wk] @ x^T, biases C-init ----------
        vf4 qk[4][4];    // [ch-tile][token-tile]; ch-tiles 0-1 = q, 2-3 = k
        #pragma unroll
        for (int mt = 0; mt < 4; ++mt) {
            const float* bsrc = (mt < 2) ? (qbs + h * 32 + mt * 16 + g * 4)
                                         : (qbs + 256 + h * 32 + (mt - 2) * 16 + g * 4);
            vf4 bi = *(const vf4*)bsrc;
            #pragma unroll
            for (int nt = 0; nt < 4; ++nt) qk[mt][nt] = bi;
        }
        __builtin_amdgcn_s_setprio(1);
        #pragma unroll
        for (int ks = 0; ks < 8; ++ks) {
            vbf8 w0 = rdW(0, c, ks);
            vbf8 w1 = rdW(0, 16 + c, ks);
            vbf8 w2 = rdW(1, c, ks);
            vbf8 w3 = rdW(1, 16 + c, ks);
            #pragma unroll
            for (int nt = 0; nt < 4; ++nt) {
                qk[0][nt] = __builtin_amdgcn_mfma_f32_16x16x32_bf16(w0, xf[nt][ks], qk[0][nt], 0, 0, 0);
                qk[1][nt] = __builtin_amdgcn_mfma_f32_16x16x32_bf16(w1, xf[nt][ks], qk[1][nt], 0, 0, 0);
                qk[2][nt] = __builtin_amdgcn_mfma_f32_16x16x32_bf16(w2, xf[nt][ks], qk[2][nt], 0, 0, 0);
                qk[3][nt] = __builtin_amdgcn_mfma_f32_16x16x32_bf16(w3, xf[nt][ks], qk[3][nt], 0, 0, 0);
            }
        }
        __builtin_amdgcn_s_setprio(0);
        vbf8 qf[4], kf[4];
        #pragma unroll
        for (int nt = 0; nt < 4; ++nt) qf[nt] = xpose(qk[0][nt], qk[1][nt], odd);
        #pragma unroll
        for (int nt = 0; nt < 4; ++nt) kf[nt] = xpose(qk[2][nt], qk[3][nt], odd);

        // ---------- v = x @ Wv^T, bias as C-init (splat over rows) ----------
        vbf8 vfr[2][2];           // [hd-tile][key-block]
        {
            vf4 va[4][2];
            #pragma unroll
            for (int nv = 0; nv < 2; ++nv) {
                const float vb = qbs[512 + h * 32 + nv * 16 + c];
                vf4 bi = {vb, vb, vb, vb};
                #pragma unroll
                for (int mt = 0; mt < 4; ++mt) va[mt][nv] = bi;
            }
            __builtin_amdgcn_s_setprio(1);
            #pragma unroll
            for (int ks = 0; ks < 8; ++ks) {
                vbf8 v0 = rdW(2, c, ks);
                vbf8 v1 = rdW(2, 16 + c, ks);
                #pragma unroll
                for (int mt = 0; mt < 4; ++mt) {
                    va[mt][0] = __builtin_amdgcn_mfma_f32_16x16x32_bf16(xf[mt][ks], v0, va[mt][0], 0, 0, 0);
                    va[mt][1] = __builtin_amdgcn_mfma_f32_16x16x32_bf16(xf[mt][ks], v1, va[mt][1], 0, 0, 0);
                }
            }
            __builtin_amdgcn_s_setprio(0);
            #pragma unroll
            for (int nv = 0; nv < 2; ++nv)
                #pragma unroll
                for (int kp = 0; kp < 2; ++kp)
                    vfr[nv][kp] = xpose(va[2 * kp][nv], va[2 * kp + 1][nv], odd);
        }

        // ---------- S^T = k @ q^T, bias as C-init ----------
        const char* bb = wb + 49152;
        vf4 st[4][4];     // [key-tile][q-tile]: col=q(c), row=key(4g+r)
        #pragma unroll
        for (int nq = 0; nq < 4; ++nq) {
            const int row = nq * 16 + c;
            #pragma unroll
            for (int mk = 0; mk < 4; ++mk)
                st[mk][nq] = *(const vf4*)(bb + row * 256 + (((mk * 64) + g * 16) ^ ((row & 7) << 4)));
        }
        __builtin_amdgcn_s_setprio(1);
        #pragma unroll
        for (int mk = 0; mk < 4; ++mk)
            #pragma unroll
            for (int nq = 0; nq < 4; ++nq)
                st[mk][nq] = __builtin_amdgcn_mfma_f32_16x16x32_bf16(kf[mk], qf[nq], st[mk][nq], 0, 0, 0);
        __builtin_amdgcn_s_setprio(0);

        // ---------- per-q-tile fused tail: softmax -> pT -> PV -> write ----------
        #pragma unroll
        for (int nq = 0; nq < 4; ++nq) {
            float mx = -3e38f;
            #pragma unroll
            for (int mk = 0; mk < 4; ++mk)
                #pragma unroll
                for (int r = 0; r < 4; ++r) mx = fmaxf(mx, st[mk][nq][r]);
            mx = fmaxf(mx, __shfl_xor(mx, 16, 64));
            mx = fmaxf(mx, __shfl_xor(mx, 32, 64));
            float sum = 0.f;
            #pragma unroll
            for (int mk = 0; mk < 4; ++mk)
                #pragma unroll
                for (int r = 0; r < 4; ++r) {
                    float p = exp2f(st[mk][nq][r] - mx);
                    st[mk][nq][r] = p;
                    sum += p;
                }
            sum += __shfl_xor(sum, 16, 64);
            sum += __shfl_xor(sum, 32, 64);
            const float linv = 1.f / sum;

            vbf8 p0 = xpose(st[0][nq], st[1][nq], odd);
            vbf8 p1 = xpose(st[2][nq], st[3][nq], odd);

            vf4 o0 = {0.f, 0.f, 0.f, 0.f}, o1 = {0.f, 0.f, 0.f, 0.f};
            o0 = __builtin_amdgcn_mfma_f32_16x16x32_bf16(vfr[0][0], p0, o0, 0, 0, 0);
            o0 = __builtin_amdgcn_mfma_f32_16x16x32_bf16(vfr[0][1], p1, o0, 0, 0, 0);
            o1 = __builtin_amdgcn_mfma_f32_16x16x32_bf16(vfr[1][0], p0, o1, 0, 0, 0);
            o1 = __builtin_amdgcn_mfma_f32_16x16x32_bf16(vfr[1][1], p1, o1, 0, 0, 0);

            #pragma unroll
            for (int r = 0; r < 4; ++r) { o0[r] *= linv; o1[r] *= linv; }
            vbf8 o = xpose(o0, o1, odd);
            const int qq = nq * 16 + c;
            if (qq < NT) {
                const int mrow = (win - win0) * NT + qq;
                *(vbf8*)(attnH + ((size_t)h * Mtot + mrow) * 32 + g * 8) = o;
            }
        }
        __syncthreads();   // next head's image staged; buffer swap safe
    }
}

// ---------------- Kernel 2: output projection GEMM (unchanged, proven) ----------------
__launch_bounds__(256, 4)
__global__ void k2_proj(const short* __restrict__ attnH,
                        const char* __restrict__ projimg,
                        const float* __restrict__ proj_b,
                        float* __restrict__ out,
                        int Mtot)
{
    __shared__ char a_lds[8192];      // [64 rows][128 B] swizzled
    __shared__ char b_lds[32768];     // [256 rows][128 B] swizzled

    const int tid  = threadIdx.x;
    const int wave = tid >> 6;
    const int lane = tid & 63;
    const int c    = lane & 15;
    const int g    = lane >> 4;
    const int m0   = (int)blockIdx.x * 64;

    vf4 acc[4][4];
    #pragma unroll
    for (int mt = 0; mt < 4; ++mt)
        #pragma unroll
        for (int nt = 0; nt < 4; ++nt) { vf4 z = {0.f,0.f,0.f,0.f}; acc[mt][nt] = z; }

    for (int kc = 0; kc < 4; ++kc) {
        __syncthreads();
        // stage A tile via DMA with swizzle-compensated per-lane source
        #pragma unroll
        for (int rr = 0; rr < 2; ++rr) {
            const int u    = tid + rr * 256;         // 512 units
            const int row  = u >> 3;
            const int sub  = u & 7;
            const int subs = sub ^ (row & 7);
            const int head = kc * 2 + (subs >> 2);
            const int kk   = (subs & 3) * 8;
            int mrow = m0 + row; if (mrow >= Mtot) mrow = Mtot - 1;
            gl_lds16(attnH + ((size_t)head * Mtot + mrow) * 32 + kk,
                     &a_lds[(rr * 256 + wave * 64) * 16]);
        }
        // stage B tile (pre-swizzled image, linear DMA)
        #pragma unroll
        for (int it = 0; it < 8; ++it) {
            const int u = tid + it * 256;            // 2048 units
            gl_lds16(projimg + (size_t)kc * 32768 + (size_t)u * 16,
                     &b_lds[(it * 256 + wave * 64) * 16]);
        }
        __syncthreads();
        #pragma unroll
        for (int ksub = 0; ksub < 2; ++ksub) {
            vbf8 af[4], bfr[4];
            #pragma unroll
            for (int mt = 0; mt < 4; ++mt) {
                const int row = mt * 16 + c;
                af[mt] = *(const vbf8*)(a_lds + row * 128 + (((ksub * 64) + g * 16) ^ ((row & 7) << 4)));
            }
            #pragma unroll
            for (int nt = 0; nt < 4; ++nt) {
                const int row = wave * 64 + nt * 16 + c;
                bfr[nt] = *(const vbf8*)(b_lds + row * 128 + (((ksub * 64) + g * 16) ^ ((row & 7) << 4)));
            }
            #pragma unroll
            for (int mt = 0; mt < 4; ++mt)
                #pragma unroll
                for (int nt = 0; nt < 4; ++nt)
                    acc[mt][nt] = __builtin_amdgcn_mfma_f32_16x16x32_bf16(af[mt], bfr[nt], acc[mt][nt], 0, 0, 0);
        }
    }
    #pragma unroll
    for (int nt = 0; nt < 4; ++nt) {
        const int n = wave * 64 + nt * 16 + c;
        const float pb = proj_b[n];
        #pragma unroll
        for (int mt = 0; mt < 4; ++mt)
            #pragma unroll
            for (int r = 0; r < 4; ++r) {
                const int m = m0 + mt * 16 + g * 4 + r;
                if (m < Mtot) out[(size_t)m * 256 + n] = acc[mt][nt][r] + pb;
            }
    }
}

extern "C" void kernel_launch(void* const* d_in, const int* in_sizes, int n_in,
                              void* d_out, int out_size, void* d_ws, size_t ws_size,
                              hipStream_t stream)
{
    const float* x      = (const float*)d_in[0];
    const float* qkv_w  = (const float*)d_in[1];
    const float* qkv_b  = (const float*)d_in[2];
    const float* proj_w = (const float*)d_in[3];
    const float* proj_b = (const float*)d_in[4];
    const float* tbl    = (const float*)d_in[5];
    float* out = (float*)d_out;
    char* ws   = (char*)d_ws;

    k0_prep<<<161, 256, 0, stream>>>(qkv_w, tbl, proj_w, qkv_b, ws);

    short* attn = (short*)(ws + ATTN_OFF);
    const float* qbs = (const float*)(ws + QBS_OFF);
    const size_t bpw = (size_t)NT * 32 * 2 * NH;   // bytes per window in attn area
    long cw = (ws_size > ATTN_OFF) ? (long)((ws_size - ATTN_OFF) / bpw) : 8;
    if (cw > 4096) cw = 4096;
    cw &= ~7L;
    if (cw < 8) cw = 8;
    for (int start = 0; start < 4096; start += (int)cw) {
        int count = 4096 - start; if (count > (int)cw) count = (int)cw;
        const int Mc = count * NT;
        k1_fused<<<count / 8, 512, 0, stream>>>(x, qbs, ws, attn, start, Mc);
        k2_proj<<<(Mc + 63) / 64, 256, 0, stream>>>(attn, ws + PROJ_OFF, proj_b,
                                                    out + (size_t)start * NT * CD, Mc);
    }
    (void)in_sizes; (void)n_in; (void)out_size;
}

// Round 8
// 332.376 us; speedup vs baseline: 1.6828x; 1.4680x over previous
//
#include <hip/hip_runtime.h>

typedef __attribute__((ext_vector_type(8))) short vbf8;   // 8 bf16 = 4 VGPR (K=32 MFMA A/B frag)
typedef __attribute__((ext_vector_type(4))) short vs4;    // 4 bf16 = 2 VGPR (K=16 MFMA A/B frag)
typedef __attribute__((ext_vector_type(4))) float vf4;    // MFMA C/D frag

#define NT 53
#define CD 256
#define NH 8
#define HIMG 65536          // per-head LDS image: Wq(16K)+Wk(16K)+Wv(16K)+biasT f32(16K)
#define PROJ_OFF 524288     // proj_w bf16 image offset in ws
#define QBS_OFF  655360     // scaled qkv_b table (768 f32)
#define ATTN_OFF 1048576    // attn intermediate offset in ws

#define LOG2E 1.4426950408889634f
#define SCALE 0.17677669529663687f   // 32^-0.5

// K=16 bf16 MFMA: builtin only (inline-asm burned us in r3). If absent,
// compile the proven r5 xpose/K32 path unchanged.
#if __has_builtin(__builtin_amdgcn_mfma_f32_16x16x16bf16_1k)
#define K16 1
#define MFMA16(a, b, c) __builtin_amdgcn_mfma_f32_16x16x16bf16_1k(a, b, c, 0, 0, 0)
#elif __has_builtin(__builtin_amdgcn_mfma_f32_16x16x16_bf16)
#define K16 1
#define MFMA16(a, b, c) __builtin_amdgcn_mfma_f32_16x16x16_bf16(a, b, c, 0, 0, 0)
#else
#define K16 0
#endif

__device__ __forceinline__ unsigned pk2(float a, float b) {
    unsigned r;
    asm("v_cvt_pk_bf16_f32 %0, %1, %2" : "=v"(r) : "v"(a), "v"(b));
    return r;
}

__device__ __forceinline__ vs4 cvt4(vf4 a) {
    union { unsigned u[2]; vs4 v; } t;
    t.u[0] = pk2(a[0], a[1]);
    t.u[1] = pk2(a[2], a[3]);
    return t.v;
}

// Transpose MFMA C-layout (col=c, rows over g,reg) into K=32-frag layout
// (lane keeps col; 8 contiguous row-elems per lane). Proven rounds 1-6.
__device__ __forceinline__ vbf8 xpose(vf4 A, vf4 B, int odd) {
    unsigned A0 = pk2(A[0], A[1]), A1 = pk2(A[2], A[3]);
    unsigned B0 = pk2(B[0], B[1]), B1 = pk2(B[2], B[3]);
    asm("v_permlane32_swap_b32 %0, %1" : "+v"(A0), "+v"(B0));
    asm("v_permlane32_swap_b32 %0, %1" : "+v"(A1), "+v"(B1));
    unsigned s0 = (unsigned)__shfl_xor((int)B0, 16, 64);
    unsigned s1 = (unsigned)__shfl_xor((int)B1, 16, 64);
    unsigned t0 = (unsigned)__shfl_xor((int)A0, 16, 64);
    unsigned t1 = (unsigned)__shfl_xor((int)A1, 16, 64);
    union { unsigned u[4]; vbf8 v; } r;
    r.u[0] = odd ? s0 : A0;
    r.u[1] = odd ? s1 : A1;
    r.u[2] = odd ? B0 : t0;
    r.u[3] = odd ? B1 : t1;
    return r.v;
}

__device__ __forceinline__ void gl_lds16(const void* g, void* l) {
    __builtin_amdgcn_global_load_lds((const __attribute__((address_space(1))) unsigned*)g,
                                     (__attribute__((address_space(3))) unsigned*)l, 16, 0, 0);
}

// ---------------- Kernel 0: prep (identical to round 5, proven) ----------------
__global__ void k0_prep(const float* __restrict__ qkv_w, const float* __restrict__ tbl,
                        const float* __restrict__ proj_w, const float* __restrict__ qkv_b,
                        char* __restrict__ ws)
{
    const int u = (int)blockIdx.x * 256 + (int)threadIdx.x;
    if (u < 24576) {
        // qkv weight images: h(8) x sec(3) x row(32) x seg(32 units of 8 bf16)
        const int h = u / 3072, rem = u - h * 3072;
        const int sec = rem >> 10, rem2 = rem & 1023;
        const int row = rem2 >> 5, seg = rem2 & 31;
        const float* src = qkv_w + ((size_t)(sec * 256 + h * 32 + row)) * 256 + seg * 8;
        const float sc = (sec == 0) ? SCALE * LOG2E : 1.0f;
        vf4 a = *(const vf4*)src;
        vf4 b = *(const vf4*)(src + 4);
        union { unsigned w[4]; vbf8 v; } r;
        r.w[0] = pk2(a[0] * sc, a[1] * sc); r.w[1] = pk2(a[2] * sc, a[3] * sc);
        r.w[2] = pk2(b[0] * sc, b[1] * sc); r.w[3] = pk2(b[2] * sc, b[3] * sc);
        char* dst = ws + (size_t)h * HIMG + sec * 16384 + row * 512 + ((seg * 16) ^ ((row & 7) << 4));
        *(vbf8*)dst = r.v;
    } else if (u < 32768) {
        // biasT images (f32, *log2e): h(8) x q(64) x seg(16 units of 4 f32); biasT[q][key]
        const int t = u - 24576;
        const int h = t >> 10, rem = t & 1023;
        const int q = rem >> 4, seg = rem & 15;
        vf4 r;
        #pragma unroll
        for (int e = 0; e < 4; ++e) {
            const int key = seg * 4 + e;
            float bv;
            if (key >= NT) bv = -1e30f;                          // mask pad keys
            else if (key < 4 || q < 4 || q >= NT) bv = 0.0f;     // carrier rows/cols
            else {
                const int i = q - 4, j = key - 4;
                const int idx = ((i / 7) - (j / 7) + 6) * 13 + ((i % 7) - (j % 7) + 6);
                bv = tbl[idx * NH + h] * LOG2E;
            }
            r[e] = bv;
        }
        char* dst = ws + (size_t)h * HIMG + 49152 + q * 256 + ((seg * 16) ^ ((q & 7) << 4));
        *(vf4*)dst = r;
    } else if (u < 40960) {
        // proj_w bf16 image: kc(4) x row(256) x seg(8)
        const int t = u - 32768;
        const int kc = t >> 11, rem = t & 2047;
        const int row = rem >> 3, seg = rem & 7;
        const float* src = proj_w + (size_t)row * 256 + kc * 64 + seg * 8;
        vf4 a = *(const vf4*)src;
        vf4 b = *(const vf4*)(src + 4);
        union { unsigned w[4]; vbf8 v; } r;
        r.w[0] = pk2(a[0], a[1]); r.w[1] = pk2(a[2], a[3]);
        r.w[2] = pk2(b[0], b[1]); r.w[3] = pk2(b[2], b[3]);
        char* dst = ws + PROJ_OFF + kc * 32768 + row * 128 + ((seg * 16) ^ ((row & 7) << 4));
        *(vbf8*)dst = r.v;
    } else if (u < 41152) {
        // scaled qkv_b: [0,256) *scale*log2e (Q), rest raw
        const int i = (u - 40960) * 4;
        float* dst = (float*)(ws + QBS_OFF);
        #pragma unroll
        for (int e = 0; e < 4; ++e) {
            const int j = i + e;
            dst[j] = qkv_b[j] * (j < 256 ? SCALE * LOG2E : 1.0f);
        }
    }
}

// ---------------- Kernel 1: fused QKV + windowed attention ----------------
// Exact round-5 structure (512 thr, 8 waves, window/wave, double-buffered head
// image, separate q/k/v clusters). Single change: when the K=16 bf16 MFMA
// builtin exists, S^T and PV use it — the C-layout of q/k/v/S accumulators IS
// the K=16 frag layout (k = 4*(lane>>4)+j), so frag prep is pure cvt_pk and
// 20 of 24 xposes/head disappear.
__launch_bounds__(512, 2)
__global__ void k1_fused(const float* __restrict__ x,
                         const float* __restrict__ qbs,
                         const char* __restrict__ himg,
                         short* __restrict__ attnH,
                         int win0, int Mtot)
{
    __shared__ char lds[2][HIMG];

    const int tid  = threadIdx.x;
    const int wave = tid >> 6;
    const int lane = tid & 63;
    const int c    = lane & 15;
    const int g    = lane >> 4;
    const int odd  = g & 1;
    const int win  = win0 + (int)blockIdx.x * 8 + wave;

    auto stage = [&](int h, int buf) {
        const char* src = himg + (size_t)h * HIMG;
        #pragma unroll
        for (int i = 0; i < 8; ++i) {
            const int u = tid + i * 512;                       // 16B unit index
            gl_lds16(src + (size_t)u * 16, &lds[buf][(i * 512 + wave * 64) * 16]);
        }
    };

    stage(0, 0);   // prologue: head-0 image

    // ---- x fragments: xf[t16][ks]: lane holds x[t16*16+c][ks*32+g*8 .. +8] (bf16)
    vbf8 xf[4][8];
    {
        const float* xb = x + (size_t)win * (NT * CD);
        #pragma unroll
        for (int mt = 0; mt < 4; ++mt) {
            const int row = mt * 16 + c;
            const float* src = xb + row * CD + g * 8;
            #pragma unroll
            for (int ks = 0; ks < 8; ++ks) {
                vbf8 z = {0, 0, 0, 0, 0, 0, 0, 0};
                if (row < NT) {
                    vf4 a = *(const vf4*)(src + ks * 32);
                    vf4 b = *(const vf4*)(src + ks * 32 + 4);
                    union { unsigned w[4]; vbf8 v; } r;
                    r.w[0] = pk2(a[0], a[1]); r.w[1] = pk2(a[2], a[3]);
                    r.w[2] = pk2(b[0], b[1]); r.w[3] = pk2(b[2], b[3]);
                    z = r.v;
                }
                xf[mt][ks] = z;
            }
        }
    }
    __syncthreads();   // head-0 image staged (barrier drains vmcnt)

    #pragma unroll 1
    for (int h = 0; h < NH; ++h) {
        const int cur = h & 1;
        if (h < 7) stage(h + 1, cur ^ 1);          // prefetch next head under compute
        const char* wb = lds[cur];

        auto rdW = [&](int sec, int rr, int ks) -> vbf8 {
            const int byte = sec * 16384 + rr * 512 + (((ks * 64) + g * 16) ^ ((rr & 7) << 4));
            return *(const vbf8*)(wb + byte);
        };

        // ---------- qT = (scale*log2e*Wq) @ x^T, bias as C-init ----------
        vf4 qa[2][4];
        #pragma unroll
        for (int mt = 0; mt < 2; ++mt) {
            vf4 bi = *(const vf4*)(qbs + h * 32 + mt * 16 + g * 4);
            #pragma unroll
            for (int nt = 0; nt < 4; ++nt) qa[mt][nt] = bi;
        }
        __builtin_amdgcn_s_setprio(1);
        #pragma unroll
        for (int mt = 0; mt < 2; ++mt)
            #pragma unroll
            for (int ks = 0; ks < 8; ++ks) {
                vbf8 wf = rdW(0, mt * 16 + c, ks);
                #pragma unroll
                for (int nt = 0; nt < 4; ++nt)
                    qa[mt][nt] = __builtin_amdgcn_mfma_f32_16x16x32_bf16(wf, xf[nt][ks], qa[mt][nt], 0, 0, 0);
            }
        __builtin_amdgcn_s_setprio(0);
#if K16
        vs4 qaF[2][4];     // [ch-tile(K-step)][token-tile]
        #pragma unroll
        for (int md = 0; md < 2; ++md)
            #pragma unroll
            for (int nt = 0; nt < 4; ++nt) qaF[md][nt] = cvt4(qa[md][nt]);
#else
        vbf8 qf[4];
        #pragma unroll
        for (int nt = 0; nt < 4; ++nt) qf[nt] = xpose(qa[0][nt], qa[1][nt], odd);
#endif

        // ---------- kT = Wk @ x^T, bias as C-init ----------
        vf4 ka[2][4];
        #pragma unroll
        for (int mt = 0; mt < 2; ++mt) {
            vf4 bi = *(const vf4*)(qbs + 256 + h * 32 + mt * 16 + g * 4);
            #pragma unroll
            for (int nt = 0; nt < 4; ++nt) ka[mt][nt] = bi;
        }
        __builtin_amdgcn_s_setprio(1);
        #pragma unroll
        for (int mt = 0; mt < 2; ++mt)
            #pragma unroll
            for (int ks = 0; ks < 8; ++ks) {
                vbf8 wf = rdW(1, mt * 16 + c, ks);
                #pragma unroll
                for (int nt = 0; nt < 4; ++nt)
                    ka[mt][nt] = __builtin_amdgcn_mfma_f32_16x16x32_bf16(wf, xf[nt][ks], ka[mt][nt], 0, 0, 0);
            }
        __builtin_amdgcn_s_setprio(0);
#if K16
        vs4 kaF[2][4];
        #pragma unroll
        for (int md = 0; md < 2; ++md)
            #pragma unroll
            for (int nt = 0; nt < 4; ++nt) kaF[md][nt] = cvt4(ka[md][nt]);
#else
        vbf8 kf[4];
        #pragma unroll
        for (int nt = 0; nt < 4; ++nt) kf[nt] = xpose(ka[0][nt], ka[1][nt], odd);
#endif

        // ---------- v = x @ Wv^T, bias as C-init (splat over rows) ----------
#if K16
        vs4 vaF[2][4];            // [hd-tile][key-tile(K-step)]
#else
        vbf8 vfr[2][2];           // [hd-tile][key-block]
#endif
        {
            vf4 va[4][2];
            #pragma unroll
            for (int nv = 0; nv < 2; ++nv) {
                const float vb = qbs[512 + h * 32 + nv * 16 + c];
                vf4 bi = {vb, vb, vb, vb};
                #pragma unroll
                for (int mt = 0; mt < 4; ++mt) va[mt][nv] = bi;
            }
            __builtin_amdgcn_s_setprio(1);
            #pragma unroll
            for (int nv = 0; nv < 2; ++nv)
                #pragma unroll
                for (int ks = 0; ks < 8; ++ks) {
                    vbf8 wf = rdW(2, nv * 16 + c, ks);
                    #pragma unroll
                    for (int mt = 0; mt < 4; ++mt)
                        va[mt][nv] = __builtin_amdgcn_mfma_f32_16x16x32_bf16(xf[mt][ks], wf, va[mt][nv], 0, 0, 0);
                }
            __builtin_amdgcn_s_setprio(0);
            #pragma unroll
            for (int nv = 0; nv < 2; ++nv)
#if K16
                #pragma unroll
                for (int kt = 0; kt < 4; ++kt) vaF[nv][kt] = cvt4(va[kt][nv]);
#else
                #pragma unroll
                for (int kp = 0; kp < 2; ++kp)
                    vfr[nv][kp] = xpose(va[2 * kp][nv], va[2 * kp + 1][nv], odd);
#endif
        }

        // ---------- S^T = k @ q^T, bias as C-init ----------
        const char* bb = wb + 49152;
        vf4 st[4][4];     // [key-tile][q-tile]: col=q(c), row=key(4g+r)
        #pragma unroll
        for (int nq = 0; nq < 4; ++nq) {
            const int row = nq * 16 + c;
            #pragma unroll
            for (int mk = 0; mk < 4; ++mk)
                st[mk][nq] = *(const vf4*)(bb + row * 256 + (((mk * 64) + g * 16) ^ ((row & 7) << 4)));
        }
        __builtin_amdgcn_s_setprio(1);
#if K16
        #pragma unroll
        for (int md = 0; md < 2; ++md)
            #pragma unroll
            for (int mk = 0; mk < 4; ++mk)
                #pragma unroll
                for (int nq = 0; nq < 4; ++nq)
                    st[mk][nq] = MFMA16(kaF[md][mk], qaF[md][nq], st[mk][nq]);
#else
        #pragma unroll
        for (int mk = 0; mk < 4; ++mk)
            #pragma unroll
            for (int nq = 0; nq < 4; ++nq)
                st[mk][nq] = __builtin_amdgcn_mfma_f32_16x16x32_bf16(kf[mk], qf[nq], st[mk][nq], 0, 0, 0);
#endif
        __builtin_amdgcn_s_setprio(0);

        // ---------- softmax over keys (exp2 domain) ----------
        float linv[4];
        #pragma unroll
        for (int nq = 0; nq < 4; ++nq) {
            float mx = -3e38f;
            #pragma unroll
            for (int mk = 0; mk < 4; ++mk)
                #pragma unroll
                for (int r = 0; r < 4; ++r) mx = fmaxf(mx, st[mk][nq][r]);
            mx = fmaxf(mx, __shfl_xor(mx, 16, 64));
            mx = fmaxf(mx, __shfl_xor(mx, 32, 64));
            float sum = 0.f;
            #pragma unroll
            for (int mk = 0; mk < 4; ++mk)
                #pragma unroll
                for (int r = 0; r < 4; ++r) {
                    float p = exp2f(st[mk][nq][r] - mx);
                    st[mk][nq][r] = p;
                    sum += p;
                }
            sum += __shfl_xor(sum, 16, 64);
            sum += __shfl_xor(sum, 32, 64);
            linv[nq] = 1.f / sum;
        }

        // ---------- pT frags + out^T = vT @ pT ----------
        vf4 ot[2][4];
        #pragma unroll
        for (int mt = 0; mt < 2; ++mt)
            #pragma unroll
            for (int nq = 0; nq < 4; ++nq) { vf4 z = {0.f,0.f,0.f,0.f}; ot[mt][nq] = z; }
#if K16
        vs4 pfr[4][4];    // [key-tile(K-step)][q-tile]
        #pragma unroll
        for (int mk = 0; mk < 4; ++mk)
            #pragma unroll
            for (int nq = 0; nq < 4; ++nq) pfr[mk][nq] = cvt4(st[mk][nq]);
        __builtin_amdgcn_s_setprio(1);
        #pragma unroll
        for (int kt = 0; kt < 4; ++kt)
            #pragma unroll
            for (int nv = 0; nv < 2; ++nv)
                #pragma unroll
                for (int nq = 0; nq < 4; ++nq)
                    ot[nv][nq] = MFMA16(vaF[nv][kt], pfr[kt][nq], ot[nv][nq]);
        __builtin_amdgcn_s_setprio(0);
#else
        vbf8 pfr[4][2];
        #pragma unroll
        for (int nq = 0; nq < 4; ++nq)
            #pragma unroll
            for (int kp = 0; kp < 2; ++kp)
                pfr[nq][kp] = xpose(st[2 * kp][nq], st[2 * kp + 1][nq], odd);
        __builtin_amdgcn_s_setprio(1);
        #pragma unroll
        for (int kp = 0; kp < 2; ++kp)
            #pragma unroll
            for (int mt = 0; mt < 2; ++mt)
                #pragma unroll
                for (int nq = 0; nq < 4; ++nq)
                    ot[mt][nq] = __builtin_amdgcn_mfma_f32_16x16x32_bf16(vfr[mt][kp], pfr[nq][kp], ot[mt][nq], 0, 0, 0);
        __builtin_amdgcn_s_setprio(0);
#endif

        // ---------- normalize + write attnH[h][mrow][32] (16B/lane) ----------
        #pragma unroll
        for (int nq = 0; nq < 4; ++nq) {
            vf4 A = ot[0][nq], B = ot[1][nq];
            #pragma unroll
            for (int r = 0; r < 4; ++r) { A[r] *= linv[nq]; B[r] *= linv[nq]; }
            vbf8 o = xpose(A, B, odd);
            const int qq = nq * 16 + c;
            if (qq < NT) {
                const int mrow = (win - win0) * NT + qq;
                *(vbf8*)(attnH + ((size_t)h * Mtot + mrow) * 32 + g * 8) = o;
            }
        }
        __syncthreads();   // next head's image staged; buffer swap safe
    }
}

// ---------------- Kernel 2: output projection GEMM (unchanged, proven) ----------------
__launch_bounds__(256, 4)
__global__ void k2_proj(const short* __restrict__ attnH,
                        const char* __restrict__ projimg,
                        const float* __restrict__ proj_b,
                        float* __restrict__ out,
                        int Mtot)
{
    __shared__ char a_lds[8192];      // [64 rows][128 B] swizzled
    __shared__ char b_lds[32768];     // [256 rows][128 B] swizzled

    const int tid  = threadIdx.x;
    const int wave = tid >> 6;
    const int lane = tid & 63;
    const int c    = lane & 15;
    const int g    = lane >> 4;
    const int m0   = (int)blockIdx.x * 64;

    vf4 acc[4][4];
    #pragma unroll
    for (int mt = 0; mt < 4; ++mt)
        #pragma unroll
        for (int nt = 0; nt < 4; ++nt) { vf4 z = {0.f,0.f,0.f,0.f}; acc[mt][nt] = z; }

    for (int kc = 0; kc < 4; ++kc) {
        __syncthreads();
        // stage A tile via DMA with swizzle-compensated per-lane source
        #pragma unroll
        for (int rr = 0; rr < 2; ++rr) {
            const int u    = tid + rr * 256;         // 512 units
            const int row  = u >> 3;
            const int sub  = u & 7;
            const int subs = sub ^ (row & 7);
            const int head = kc * 2 + (subs >> 2);
            const int kk   = (subs & 3) * 8;
            int mrow = m0 + row; if (mrow >= Mtot) mrow = Mtot - 1;
            gl_lds16(attnH + ((size_t)head * Mtot + mrow) * 32 + kk,
                     &a_lds[(rr * 256 + wave * 64) * 16]);
        }
        // stage B tile (pre-swizzled image, linear DMA)
        #pragma unroll
        for (int it = 0; it < 8; ++it) {
            const int u = tid + it * 256;            // 2048 units
            gl_lds16(projimg + (size_t)kc * 32768 + (size_t)u * 16,
                     &b_lds[(it * 256 + wave * 64) * 16]);
        }
        __syncthreads();
        #pragma unroll
        for (int ksub = 0; ksub < 2; ++ksub) {
            vbf8 af[4], bfr[4];
            #pragma unroll
            for (int mt = 0; mt < 4; ++mt) {
                const int row = mt * 16 + c;
                af[mt] = *(const vbf8*)(a_lds + row * 128 + (((ksub * 64) + g * 16) ^ ((row & 7) << 4)));
            }
            #pragma unroll
            for (int nt = 0; nt < 4; ++nt) {
                const int row = wave * 64 + nt * 16 + c;
                bfr[nt] = *(const vbf8*)(b_lds + row * 128 + (((ksub * 64) + g * 16) ^ ((row & 7) << 4)));
            }
            #pragma unroll
            for (int mt = 0; mt < 4; ++mt)
                #pragma unroll
                for (int nt = 0; nt < 4; ++nt)
                    acc[mt][nt] = __builtin_amdgcn_mfma_f32_16x16x32_bf16(af[mt], bfr[nt], acc[mt][nt], 0, 0, 0);
        }
    }
    #pragma unroll
    for (int nt = 0; nt < 4; ++nt) {
        const int n = wave * 64 + nt * 16 + c;
        const float pb = proj_b[n];
        #pragma unroll
        for (int mt = 0; mt < 4; ++mt)
            #pragma unroll
            for (int r = 0; r < 4; ++r) {
                const int m = m0 + mt * 16 + g * 4 + r;
                if (m < Mtot) out[(size_t)m * 256 + n] = acc[mt][nt][r] + pb;
            }
    }
}

extern "C" void kernel_launch(void* const* d_in, const int* in_sizes, int n_in,
                              void* d_out, int out_size, void* d_ws, size_t ws_size,
                              hipStream_t stream)
{
    const float* x      = (const float*)d_in[0];
    const float* qkv_w  = (const float*)d_in[1];
    const float* qkv_b  = (const float*)d_in[2];
    const float* proj_w = (const float*)d_in[3];
    const float* proj_b = (const float*)d_in[4];
    const float* tbl    = (const float*)d_in[5];
    float* out = (float*)d_out;
    char* ws   = (char*)d_ws;

    k0_prep<<<161, 256, 0, stream>>>(qkv_w, tbl, proj_w, qkv_b, ws);

    short* attn = (short*)(ws + ATTN_OFF);
    const float* qbs = (const float*)(ws + QBS_OFF);
    const size_t bpw = (size_t)NT * 32 * 2 * NH;   // bytes per window in attn area
    long cw = (ws_size > ATTN_OFF) ? (long)((ws_size - ATTN_OFF) / bpw) : 8;
    if (cw > 4096) cw = 4096;
    cw &= ~7L;
    if (cw < 8) cw = 8;
    for (int start = 0; start < 4096; start += (int)cw) {
        int count = 4096 - start; if (count > (int)cw) count = (int)cw;
        const int Mc = count * NT;
        k1_fused<<<count / 8, 512, 0, stream>>>(x, qbs, ws, attn, start, Mc);
        k2_proj<<<(Mc + 63) / 64, 256, 0, stream>>>(attn, ws + PROJ_OFF, proj_b,
                                                    out + (size_t)start * NT * CD, Mc);
    }
    (void)in_sizes; (void)n_in; (void)out_size;
}

// Round 13
// 329.323 us; speedup vs baseline: 1.6984x; 1.0093x over previous
//
#include <hip/hip_runtime.h>

typedef __attribute__((ext_vector_type(8))) short vbf8;   // 8 bf16 = 4 VGPR (K=32 MFMA A/B frag)
typedef __attribute__((ext_vector_type(4))) short vs4;    // 4 bf16 = 2 VGPR (K=16 MFMA A/B frag)
typedef __attribute__((ext_vector_type(4))) float vf4;    // MFMA C/D frag

#define NT 53
#define CD 256
#define NH 8
#define HIMG 65536          // per-head LDS image: Wq(16K)+Wk(16K)+Wv(16K)+biasT f32(16K)
#define PROJ_OFF 524288     // proj_w bf16 image offset in ws
#define QBS_OFF  655360     // scaled qkv_b table (768 f32)
#define ATTN_OFF 1048576    // attn intermediate offset in ws

#define LOG2E 1.4426950408889634f
#define SCALE 0.17677669529663687f   // 32^-0.5

// K=16 bf16 MFMA: builtin only (inline-asm burned us in r3). If absent,
// compile the proven r5 xpose/K32 path unchanged.
#if __has_builtin(__builtin_amdgcn_mfma_f32_16x16x16bf16_1k)
#define K16 1
#define MFMA16(a, b, c) __builtin_amdgcn_mfma_f32_16x16x16bf16_1k(a, b, c, 0, 0, 0)
#elif __has_builtin(__builtin_amdgcn_mfma_f32_16x16x16_bf16)
#define K16 1
#define MFMA16(a, b, c) __builtin_amdgcn_mfma_f32_16x16x16_bf16(a, b, c, 0, 0, 0)
#else
#define K16 0
#endif

__device__ __forceinline__ unsigned pk2(float a, float b) {
    unsigned r;
    asm("v_cvt_pk_bf16_f32 %0, %1, %2" : "=v"(r) : "v"(a), "v"(b));
    return r;
}

__device__ __forceinline__ vs4 cvt4(vf4 a) {
    union { unsigned u[2]; vs4 v; } t;
    t.u[0] = pk2(a[0], a[1]);
    t.u[1] = pk2(a[2], a[3]);
    return t.v;
}

// Transpose MFMA C-layout (col=c, rows over g,reg) into K=32-frag layout
// (lane keeps col; 8 contiguous row-elems per lane). Proven rounds 1-6.
__device__ __forceinline__ vbf8 xpose(vf4 A, vf4 B, int odd) {
    unsigned A0 = pk2(A[0], A[1]), A1 = pk2(A[2], A[3]);
    unsigned B0 = pk2(B[0], B[1]), B1 = pk2(B[2], B[3]);
    asm("v_permlane32_swap_b32 %0, %1" : "+v"(A0), "+v"(B0));
    asm("v_permlane32_swap_b32 %0, %1" : "+v"(A1), "+v"(B1));
    unsigned s0 = (unsigned)__shfl_xor((int)B0, 16, 64);
    unsigned s1 = (unsigned)__shfl_xor((int)B1, 16, 64);
    unsigned t0 = (unsigned)__shfl_xor((int)A0, 16, 64);
    unsigned t1 = (unsigned)__shfl_xor((int)A1, 16, 64);
    union { unsigned u[4]; vbf8 v; } r;
    r.u[0] = odd ? s0 : A0;
    r.u[1] = odd ? s1 : A1;
    r.u[2] = odd ? B0 : t0;
    r.u[3] = odd ? B1 : t1;
    return r.v;
}

__device__ __forceinline__ void gl_lds16(const void* g, void* l) {
    __builtin_amdgcn_global_load_lds((const __attribute__((address_space(1))) unsigned*)g,
                                     (__attribute__((address_space(3))) unsigned*)l, 16, 0, 0);
}

// ---------------- Kernel 0: prep (identical to round 5, proven) ----------------
__global__ void k0_prep(const float* __restrict__ qkv_w, const float* __restrict__ tbl,
                        const float* __restrict__ proj_w, const float* __restrict__ qkv_b,
                        char* __restrict__ ws)
{
    const int u = (int)blockIdx.x * 256 + (int)threadIdx.x;
    if (u < 24576) {
        // qkv weight images: h(8) x sec(3) x row(32) x seg(32 units of 8 bf16)
        const int h = u / 3072, rem = u - h * 3072;
        const int sec = rem >> 10, rem2 = rem & 1023;
        const int row = rem2 >> 5, seg = rem2 & 31;
        const float* src = qkv_w + ((size_t)(sec * 256 + h * 32 + row)) * 256 + seg * 8;
        const float sc = (sec == 0) ? SCALE * LOG2E : 1.0f;
        vf4 a = *(const vf4*)src;
        vf4 b = *(const vf4*)(src + 4);
        union { unsigned w[4]; vbf8 v; } r;
        r.w[0] = pk2(a[0] * sc, a[1] * sc); r.w[1] = pk2(a[2] * sc, a[3] * sc);
        r.w[2] = pk2(b[0] * sc, b[1] * sc); r.w[3] = pk2(b[2] * sc, b[3] * sc);
        char* dst = ws + (size_t)h * HIMG + sec * 16384 + row * 512 + ((seg * 16) ^ ((row & 7) << 4));
        *(vbf8*)dst = r.v;
    } else if (u < 32768) {
        // biasT images (f32, *log2e): h(8) x q(64) x seg(16 units of 4 f32); biasT[q][key]
        const int t = u - 24576;
        const int h = t >> 10, rem = t & 1023;
        const int q = rem >> 4, seg = rem & 15;
        vf4 r;
        #pragma unroll
        for (int e = 0; e < 4; ++e) {
            const int key = seg * 4 + e;
            float bv;
            if (key >= NT) bv = -1e30f;                          // mask pad keys
            else if (key < 4 || q < 4 || q >= NT) bv = 0.0f;     // carrier rows/cols
            else {
                const int i = q - 4, j = key - 4;
                const int idx = ((i / 7) - (j / 7) + 6) * 13 + ((i % 7) - (j % 7) + 6);
                bv = tbl[idx * NH + h] * LOG2E;
            }
            r[e] = bv;
        }
        char* dst = ws + (size_t)h * HIMG + 49152 + q * 256 + ((seg * 16) ^ ((q & 7) << 4));
        *(vf4*)dst = r;
    } else if (u < 40960) {
        // proj_w bf16 image: kc(4) x row(256) x seg(8)
        const int t = u - 32768;
        const int kc = t >> 11, rem = t & 2047;
        const int row = rem >> 3, seg = rem & 7;
        const float* src = proj_w + (size_t)row * 256 + kc * 64 + seg * 8;
        vf4 a = *(const vf4*)src;
        vf4 b = *(const vf4*)(src + 4);
        union { unsigned w[4]; vbf8 v; } r;
        r.w[0] = pk2(a[0], a[1]); r.w[1] = pk2(a[2], a[3]);
        r.w[2] = pk2(b[0], b[1]); r.w[3] = pk2(b[2], b[3]);
        char* dst = ws + PROJ_OFF + kc * 32768 + row * 128 + ((seg * 16) ^ ((row & 7) << 4));
        *(vbf8*)dst = r.v;
    } else if (u < 41152) {
        // scaled qkv_b: [0,256) *scale*log2e (Q), rest raw
        const int i = (u - 40960) * 4;
        float* dst = (float*)(ws + QBS_OFF);
        #pragma unroll
        for (int e = 0; e < 4; ++e) {
            const int j = i + e;
            dst[j] = qkv_b[j] * (j < 256 ? SCALE * LOG2E : 1.0f);
        }
    }
}

// ---------------- Kernel 1: fused QKV + windowed attention ----------------
// Exact round-5 structure (512 thr, 8 waves, window/wave, double-buffered head
// image, separate q/k/v clusters). Single change: when the K=16 bf16 MFMA
// builtin exists, S^T and PV use it — the C-layout of q/k/v/S accumulators IS
// the K=16 frag layout (k = 4*(lane>>4)+j), so frag prep is pure cvt_pk and
// 20 of 24 xposes/head disappear.
__launch_bounds__(512, 2)
__global__ void k1_fused(const float* __restrict__ x,
                         const float* __restrict__ qbs,
                         const char* __restrict__ himg,
                         short* __restrict__ attnH,
                         int win0, int Mtot)
{
    __shared__ char lds[2][HIMG];

    const int tid  = threadIdx.x;
    const int wave = tid >> 6;
    const int lane = tid & 63;
    const int c    = lane & 15;
    const int g    = lane >> 4;
    const int odd  = g & 1;
    const int win  = win0 + (int)blockIdx.x * 8 + wave;

    auto stage = [&](int h, int buf) {
        const char* src = himg + (size_t)h * HIMG;
        #pragma unroll
        for (int i = 0; i < 8; ++i) {
            const int u = tid + i * 512;                       // 16B unit index
            gl_lds16(src + (size_t)u * 16, &lds[buf][(i * 512 + wave * 64) * 16]);
        }
    };

    stage(0, 0);   // prologue: head-0 image

    // ---- x fragments: xf[t16][ks]: lane holds x[t16*16+c][ks*32+g*8 .. +8] (bf16)
    vbf8 xf[4][8];
    {
        const float* xb = x + (size_t)win * (NT * CD);
        #pragma unroll
        for (int mt = 0; mt < 4; ++mt) {
            const int row = mt * 16 + c;
            const float* src = xb + row * CD + g * 8;
            #pragma unroll
            for (int ks = 0; ks < 8; ++ks) {
                vbf8 z = {0, 0, 0, 0, 0, 0, 0, 0};
                if (row < NT) {
                    vf4 a = *(const vf4*)(src + ks * 32);
                    vf4 b = *(const vf4*)(src + ks * 32 + 4);
                    union { unsigned w[4]; vbf8 v; } r;
                    r.w[0] = pk2(a[0], a[1]); r.w[1] = pk2(a[2], a[3]);
                    r.w[2] = pk2(b[0], b[1]); r.w[3] = pk2(b[2], b[3]);
                    z = r.v;
                }
                xf[mt][ks] = z;
            }
        }
    }
    __syncthreads();   // head-0 image staged (barrier drains vmcnt)

    #pragma unroll 1
    for (int h = 0; h < NH; ++h) {
        const int cur = h & 1;
        if (h < 7) stage(h + 1, cur ^ 1);          // prefetch next head under compute
        const char* wb = lds[cur];

        auto rdW = [&](int sec, int rr, int ks) -> vbf8 {
            const int byte = sec * 16384 + rr * 512 + (((ks * 64) + g * 16) ^ ((rr & 7) << 4));
            return *(const vbf8*)(wb + byte);
        };

        // ---------- qT = (scale*log2e*Wq) @ x^T, bias as C-init ----------
        vf4 qa[2][4];
        #pragma unroll
        for (int mt = 0; mt < 2; ++mt) {
            vf4 bi = *(const vf4*)(qbs + h * 32 + mt * 16 + g * 4);
            #pragma unroll
            for (int nt = 0; nt < 4; ++nt) qa[mt][nt] = bi;
        }
        __builtin_amdgcn_s_setprio(1);
        #pragma unroll
        for (int mt = 0; mt < 2; ++mt)
            #pragma unroll
            for (int ks = 0; ks < 8; ++ks) {
                vbf8 wf = rdW(0, mt * 16 + c, ks);
                #pragma unroll
                for (int nt = 0; nt < 4; ++nt)
                    qa[mt][nt] = __builtin_amdgcn_mfma_f32_16x16x32_bf16(wf, xf[nt][ks], qa[mt][nt], 0, 0, 0);
            }
        __builtin_amdgcn_s_setprio(0);
#if K16
        vs4 qaF[2][4];     // [ch-tile(K-step)][token-tile]
        #pragma unroll
        for (int md = 0; md < 2; ++md)
            #pragma unroll
            for (int nt = 0; nt < 4; ++nt) qaF[md][nt] = cvt4(qa[md][nt]);
#else
        vbf8 qf[4];
        #pragma unroll
        for (int nt = 0; nt < 4; ++nt) qf[nt] = xpose(qa[0][nt], qa[1][nt], odd);
#endif

        // ---------- kT = Wk @ x^T, bias as C-init ----------
        vf4 ka[2][4];
        #pragma unroll
        for (int mt = 0; mt < 2; ++mt) {
            vf4 bi = *(const vf4*)(qbs + 256 + h * 32 + mt * 16 + g * 4);
            #pragma unroll
            for (int nt = 0; nt < 4; ++nt) ka[mt][nt] = bi;
        }
        __builtin_amdgcn_s_setprio(1);
        #pragma unroll
        for (int mt = 0; mt < 2; ++mt)
            #pragma unroll
            for (int ks = 0; ks < 8; ++ks) {
                vbf8 wf = rdW(1, mt * 16 + c, ks);
                #pragma unroll
                for (int nt = 0; nt < 4; ++nt)
                    ka[mt][nt] = __builtin_amdgcn_mfma_f32_16x16x32_bf16(wf, xf[nt][ks], ka[mt][nt], 0, 0, 0);
            }
        __builtin_amdgcn_s_setprio(0);
#if K16
        vs4 kaF[2][4];
        #pragma unroll
        for (int md = 0; md < 2; ++md)
            #pragma unroll
            for (int nt = 0; nt < 4; ++nt) kaF[md][nt] = cvt4(ka[md][nt]);
#else
        vbf8 kf[4];
        #pragma unroll
        for (int nt = 0; nt < 4; ++nt) kf[nt] = xpose(ka[0][nt], ka[1][nt], odd);
#endif

        // ---------- v = x @ Wv^T, bias as C-init (splat over rows) ----------
#if K16
        vs4 vaF[2][4];            // [hd-tile][key-tile(K-step)]
#else
        vbf8 vfr[2][2];           // [hd-tile][key-block]
#endif
        {
            vf4 va[4][2];
            #pragma unroll
            for (int nv = 0; nv < 2; ++nv) {
                const float vb = qbs[512 + h * 32 + nv * 16 + c];
                vf4 bi = {vb, vb, vb, vb};
                #pragma unroll
                for (int mt = 0; mt < 4; ++mt) va[mt][nv] = bi;
            }
            __builtin_amdgcn_s_setprio(1);
            #pragma unroll
            for (int nv = 0; nv < 2; ++nv)
                #pragma unroll
                for (int ks = 0; ks < 8; ++ks) {
                    vbf8 wf = rdW(2, nv * 16 + c, ks);
                    #pragma unroll
                    for (int mt = 0; mt < 4; ++mt)
                        va[mt][nv] = __builtin_amdgcn_mfma_f32_16x16x32_bf16(xf[mt][ks], wf, va[mt][nv], 0, 0, 0);
                }
            __builtin_amdgcn_s_setprio(0);
            #pragma unroll
            for (int nv = 0; nv < 2; ++nv)
#if K16
                #pragma unroll
                for (int kt = 0; kt < 4; ++kt) vaF[nv][kt] = cvt4(va[kt][nv]);
#else
                #pragma unroll
                for (int kp = 0; kp < 2; ++kp)
                    vfr[nv][kp] = xpose(va[2 * kp][nv], va[2 * kp + 1][nv], odd);
#endif
        }

        // ---------- S^T = k @ q^T, bias as C-init ----------
        const char* bb = wb + 49152;
        vf4 st[4][4];     // [key-tile][q-tile]: col=q(c), row=key(4g+r)
        #pragma unroll
        for (int nq = 0; nq < 4; ++nq) {
            const int row = nq * 16 + c;
            #pragma unroll
            for (int mk = 0; mk < 4; ++mk)
                st[mk][nq] = *(const vf4*)(bb + row * 256 + (((mk * 64) + g * 16) ^ ((row & 7) << 4)));
        }
        __builtin_amdgcn_s_setprio(1);
#if K16
        #pragma unroll
        for (int md = 0; md < 2; ++md)
            #pragma unroll
            for (int mk = 0; mk < 4; ++mk)
                #pragma unroll
                for (int nq = 0; nq < 4; ++nq)
                    st[mk][nq] = MFMA16(kaF[md][mk], qaF[md][nq], st[mk][nq]);
#else
        #pragma unroll
        for (int mk = 0; mk < 4; ++mk)
            #pragma unroll
            for (int nq = 0; nq < 4; ++nq)
                st[mk][nq] = __builtin_amdgcn_mfma_f32_16x16x32_bf16(kf[mk], qf[nq], st[mk][nq], 0, 0, 0);
#endif
        __builtin_amdgcn_s_setprio(0);

        // ---------- softmax over keys (exp2 domain) ----------
        float linv[4];
        #pragma unroll
        for (int nq = 0; nq < 4; ++nq) {
            float mx = -3e38f;
            #pragma unroll
            for (int mk = 0; mk < 4; ++mk)
                #pragma unroll
                for (int r = 0; r < 4; ++r) mx = fmaxf(mx, st[mk][nq][r]);
            mx = fmaxf(mx, __shfl_xor(mx, 16, 64));
            mx = fmaxf(mx, __shfl_xor(mx, 32, 64));
            float sum = 0.f;
            #pragma unroll
            for (int mk = 0; mk < 4; ++mk)
                #pragma unroll
                for (int r = 0; r < 4; ++r) {
                    float p = exp2f(st[mk][nq][r] - mx);
                    st[mk][nq][r] = p;
                    sum += p;
                }
            sum += __shfl_xor(sum, 16, 64);
            sum += __shfl_xor(sum, 32, 64);
            linv[nq] = 1.f / sum;
        }

        // ---------- pT frags + out^T = vT @ pT ----------
        vf4 ot[2][4];
        #pragma unroll
        for (int mt = 0; mt < 2; ++mt)
            #pragma unroll
            for (int nq = 0; nq < 4; ++nq) { vf4 z = {0.f,0.f,0.f,0.f}; ot[mt][nq] = z; }
#if K16
        vs4 pfr[4][4];    // [key-tile(K-step)][q-tile]
        #pragma unroll
        for (int mk = 0; mk < 4; ++mk)
            #pragma unroll
            for (int nq = 0; nq < 4; ++nq) pfr[mk][nq] = cvt4(st[mk][nq]);
        __builtin_amdgcn_s_setprio(1);
        #pragma unroll
        for (int kt = 0; kt < 4; ++kt)
            #pragma unroll
            for (int nv = 0; nv < 2; ++nv)
                #pragma unroll
                for (int nq = 0; nq < 4; ++nq)
                    ot[nv][nq] = MFMA16(vaF[nv][kt], pfr[kt][nq], ot[nv][nq]);
        __builtin_amdgcn_s_setprio(0);
#else
        vbf8 pfr[4][2];
        #pragma unroll
        for (int nq = 0; nq < 4; ++nq)
            #pragma unroll
            for (int kp = 0; kp < 2; ++kp)
                pfr[nq][kp] = xpose(st[2 * kp][nq], st[2 * kp + 1][nq], odd);
        __builtin_amdgcn_s_setprio(1);
        #pragma unroll
        for (int kp = 0; kp < 2; ++kp)
            #pragma unroll
            for (int mt = 0; mt < 2; ++mt)
                #pragma unroll
                for (int nq = 0; nq < 4; ++nq)
                    ot[mt][nq] = __builtin_amdgcn_mfma_f32_16x16x32_bf16(vfr[mt][kp], pfr[nq][kp], ot[mt][nq], 0, 0, 0);
        __builtin_amdgcn_s_setprio(0);
#endif

        // ---------- normalize + write attnH[h][mrow][32] (16B/lane) ----------
        #pragma unroll
        for (int nq = 0; nq < 4; ++nq) {
            vf4 A = ot[0][nq], B = ot[1][nq];
            #pragma unroll
            for (int r = 0; r < 4; ++r) { A[r] *= linv[nq]; B[r] *= linv[nq]; }
            vbf8 o = xpose(A, B, odd);
            const int qq = nq * 16 + c;
            if (qq < NT) {
                const int mrow = (win - win0) * NT + qq;
                *(vbf8*)(attnH + ((size_t)h * Mtot + mrow) * 32 + g * 8) = o;
            }
        }
        __syncthreads();   // next head's image staged; buffer swap safe
    }
}

// ---------------- Kernel 2: output projection GEMM (unchanged, proven) ----------------
__launch_bounds__(256, 4)
__global__ void k2_proj(const short* __restrict__ attnH,
                        const char* __restrict__ projimg,
                        const float* __restrict__ proj_b,
                        float* __restrict__ out,
                        int Mtot)
{
    __shared__ char a_lds[8192];      // [64 rows][128 B] swizzled
    __shared__ char b_lds[32768];     // [256 rows][128 B] swizzled

    const int tid  = threadIdx.x;
    const int wave = tid >> 6;
    const int lane = tid & 63;
    const int c    = lane & 15;
    const int g    = lane >> 4;
    const int m0   = (int)blockIdx.x * 64;

    vf4 acc[4][4];
    #pragma unroll
    for (int mt = 0; mt < 4; ++mt)
        #pragma unroll
        for (int nt = 0; nt < 4; ++nt) { vf4 z = {0.f,0.f,0.f,0.f}; acc[mt][nt] = z; }

    for (int kc = 0; kc < 4; ++kc) {
        __syncthreads();
        // stage A tile via DMA with swizzle-compensated per-lane source
        #pragma unroll
        for (int rr = 0; rr < 2; ++rr) {
            const int u    = tid + rr * 256;         // 512 units
            const int row  = u >> 3;
            const int sub  = u & 7;
            const int subs = sub ^ (row & 7);
            const int head = kc * 2 + (subs >> 2);
            const int kk   = (subs & 3) * 8;
            int mrow = m0 + row; if (mrow >= Mtot) mrow = Mtot - 1;
            gl_lds16(attnH + ((size_t)head * Mtot + mrow) * 32 + kk,
                     &a_lds[(rr * 256 + wave * 64) * 16]);
        }
        // stage B tile (pre-swizzled image, linear DMA)
        #pragma unroll
        for (int it = 0; it < 8; ++it) {
            const int u = tid + it * 256;            // 2048 units
            gl_lds16(projimg + (size_t)kc * 32768 + (size_t)u * 16,
                     &b_lds[(it * 256 + wave * 64) * 16]);
        }
        __syncthreads();
        #pragma unroll
        for (int ksub = 0; ksub < 2; ++ksub) {
            vbf8 af[4], bfr[4];
            #pragma unroll
            for (int mt = 0; mt < 4; ++mt) {
                const int row = mt * 16 + c;
                af[mt] = *(const vbf8*)(a_lds + row * 128 + (((ksub * 64) + g * 16) ^ ((row & 7) << 4)));
            }
            #pragma unroll
            for (int nt = 0; nt < 4; ++nt) {
                const int row = wave * 64 + nt * 16 + c;
                bfr[nt] = *(const vbf8*)(b_lds + row * 128 + (((ksub * 64) + g * 16) ^ ((row & 7) << 4)));
            }
            #pragma unroll
            for (int mt = 0; mt < 4; ++mt)
                #pragma unroll
                for (int nt = 0; nt < 4; ++nt)
                    acc[mt][nt] = __builtin_amdgcn_mfma_f32_16x16x32_bf16(af[mt], bfr[nt], acc[mt][nt], 0, 0, 0);
        }
    }
    #pragma unroll
    for (int nt = 0; nt < 4; ++nt) {
        const int n = wave * 64 + nt * 16 + c;
        const float pb = proj_b[n];
        #pragma unroll
        for (int mt = 0; mt < 4; ++mt)
            #pragma unroll
            for (int r = 0; r < 4; ++r) {
                const int m = m0 + mt * 16 + g * 4 + r;
                if (m < Mtot) out[(size_t)m * 256 + n] = acc[mt][nt][r] + pb;
            }
    }
}

extern "C" void kernel_launch(void* const* d_in, const int* in_sizes, int n_in,
                              void* d_out, int out_size, void* d_ws, size_t ws_size,
                              hipStream_t stream)
{
    const float* x      = (const float*)d_in[0];
    const float* qkv_w  = (const float*)d_in[1];
    const float* qkv_b  = (const float*)d_in[2];
    const float* proj_w = (const float*)d_in[3];
    const float* proj_b = (const float*)d_in[4];
    const float* tbl    = (const float*)d_in[5];
    float* out = (float*)d_out;
    char* ws   = (char*)d_ws;

    k0_prep<<<161, 256, 0, stream>>>(qkv_w, tbl, proj_w, qkv_b, ws);

    short* attn = (short*)(ws + ATTN_OFF);
    const float* qbs = (const float*)(ws + QBS_OFF);
    const size_t bpw = (size_t)NT * 32 * 2 * NH;   // bytes per window in attn area
    long cw = (ws_size > ATTN_OFF) ? (long)((ws_size - ATTN_OFF) / bpw) : 8;
    if (cw > 4096) cw = 4096;
    cw &= ~7L;
    if (cw < 8) cw = 8;
    for (int start = 0; start < 4096; start += (int)cw) {
        int count = 4096 - start; if (count > (int)cw) count = (int)cw;
        const int Mc = count * NT;
        k1_fused<<<count / 8, 512, 0, stream>>>(x, qbs, ws, attn, start, Mc);
        k2_proj<<<(Mc + 63) / 64, 256, 0, stream>>>(attn, ws + PROJ_OFF, proj_b,
                                                    out + (size_t)start * NT * CD, Mc);
    }
    (void)in_sizes; (void)n_in; (void)out_size;
}